// Round 5
// baseline (300.497 us; speedup 1.0000x reference)
//
#include <hip/hip_runtime.h>
#include <hip/hip_bf16.h>

typedef __attribute__((ext_vector_type(8))) short bf16x8;
typedef __attribute__((ext_vector_type(4))) short s16x4;
typedef __attribute__((ext_vector_type(4))) float f32x4;
typedef __attribute__((ext_vector_type(2))) unsigned int u32x2;

#define AS1(p) ((const __attribute__((address_space(1))) void*)(p))
#define AS3(p) ((__attribute__((address_space(3))) void*)(p))
#define EXP2(x) __builtin_amdgcn_exp2f(x)

__device__ __forceinline__ unsigned short f2bf(float f) {
  __hip_bfloat16 h = __float2bfloat16(f);
  union { __hip_bfloat16 h; unsigned short s; } u; u.h = h; return u.s;
}
__device__ __forceinline__ unsigned pack2bf(float a, float b) {
  return ((unsigned)f2bf(b) << 16) | (unsigned)f2bf(a);
}

// PV matmul: 16x16x16 bf16 MFMA — B-operand layout (col=l&15, k=(l>>4)*4+j)
// exactly matches the 16x16 D-layout of the QK^T output. No cross-lane movement.
__device__ __forceinline__ f32x4 mfma16(s16x4 a, s16x4 b, f32x4 c) {
#if __has_builtin(__builtin_amdgcn_mfma_f32_16x16x16bf16_1k)
  return __builtin_amdgcn_mfma_f32_16x16x16bf16_1k(a, b, c, 0, 0, 0);
#else
  f32x4 d = c;
  asm volatile("v_mfma_f32_16x16x16_bf16 %0, %1, %2, %0" : "+v"(d) : "v"(a), "v"(b));
  return d;
#endif
}

// ---------------- pack kernels (coalesced reads) ----------------
__global__ void pack_wqkv(const float* __restrict__ Q, const float* __restrict__ K,
                          const float* __restrict__ V, short* __restrict__ WqkvT) {
  int idx = blockIdx.x * 256 + threadIdx.x;   // 786432 threads total
  int sq = idx >> 12;                         // sel*64 + qd, 0..191
  int r = idx & 4095;
  int sel = sq >> 6, qd = sq & 63;
  const float* src = (sel == 0) ? Q : (sel == 1) ? K : V;
  float scale = (sel == 0) ? (0.03125f * 1.44269504f) : (sel == 1) ? 0.03125f : 0.25f;
  f32x4 v = *(const f32x4*)(src + (size_t)qd * 16384 + r * 4);
  int d = r >> 2, hb = (r & 3) * 4;
#pragma unroll
  for (int j = 0; j < 4; ++j)
    WqkvT[(size_t)(sel * 1024 + (hb + j) * 64 + qd) * 1024 + d] = (short)f2bf(v[j] * scale);
}

__global__ void pack_wo(const float* __restrict__ W, short* __restrict__ WoT) {
  int dcol = blockIdx.x;
  int t = threadIdx.x;  // 256 threads cover 1024 f32
  f32x4 v = *(const f32x4*)(W + (size_t)dcol * 1024 + t * 4);
  int vd = t >> 2, hb = (t & 3) * 4;
#pragma unroll
  for (int j = 0; j < 4; ++j)
    WoT[(size_t)dcol * 1024 + (hb + j) * 64 + vd] = (short)f2bf(v[j] * 0.25f);
}

__global__ void pack_xk(const float* __restrict__ x, short* __restrict__ xb) {
  int i = blockIdx.x * 256 + threadIdx.x;  // groups of 4 floats
  if (i >= 2097152) return;
  f32x4 v = ((const f32x4*)x)[i];
  s16x4 o;
#pragma unroll
  for (int j = 0; j < 4; ++j) o[j] = (short)f2bf(v[j]);
  ((s16x4*)xb)[i] = o;
}

// ---------------- GEMM: C[M,N] = A[M,K] * Bt[N,K]^T  (m97 structure) ----------------
template <int MODE>
__global__ __launch_bounds__(256) void gemm_bt(const short* __restrict__ A,
                                               const short* __restrict__ Bt,
                                               void* __restrict__ Cout,
                                               int M, int N, int K) {
  __shared__ short As[128 * 64];
  __shared__ short Bs[128 * 64];
  const int tid = threadIdx.x;
  const int l = tid & 63, w = tid >> 6;
  const int g = l >> 4, lr = l & 15;
  const int m0 = blockIdx.y * 128, n0 = blockIdx.x * 128;
  const int wm = w >> 1, wn = w & 1;
  const int sr = l >> 3, sc = (l & 7) * 8;
  f32x4 acc[4][4] = {};
  for (int k0 = 0; k0 < K; k0 += 64) {
#pragma unroll
    for (int j = 0; j < 4; ++j) {
      int r0 = (w * 4 + j) * 8;
      __builtin_amdgcn_global_load_lds(AS1(A + (size_t)(m0 + r0 + sr) * K + k0 + sc),
                                       AS3(&As[r0 * 64]), 16, 0, 0);
      __builtin_amdgcn_global_load_lds(AS1(Bt + (size_t)(n0 + r0 + sr) * K + k0 + sc),
                                       AS3(&Bs[r0 * 64]), 16, 0, 0);
    }
    __syncthreads();
#pragma unroll
    for (int kc = 0; kc < 2; ++kc) {
      bf16x8 af[4], bfr[4];
#pragma unroll
      for (int i = 0; i < 4; ++i) {
        af[i]  = *(const bf16x8*)&As[(wm * 64 + i * 16 + lr) * 64 + kc * 32 + g * 8];
        bfr[i] = *(const bf16x8*)&Bs[(wn * 64 + i * 16 + lr) * 64 + kc * 32 + g * 8];
      }
#pragma unroll
      for (int mi = 0; mi < 4; ++mi)
#pragma unroll
        for (int ni = 0; ni < 4; ++ni)
          acc[mi][ni] = __builtin_amdgcn_mfma_f32_16x16x32_bf16(af[mi], bfr[ni], acc[mi][ni], 0, 0, 0);
    }
    __syncthreads();
  }
#pragma unroll
  for (int mi = 0; mi < 4; ++mi) {
#pragma unroll
    for (int ni = 0; ni < 4; ++ni) {
#pragma unroll
      for (int j = 0; j < 4; ++j) {
        int m = m0 + wm * 64 + mi * 16 + g * 4 + j;
        int n = n0 + wn * 64 + ni * 16 + lr;
        float val = acc[mi][ni][j];
        if (MODE == 0) {
          int sel = n >> 10, h = (n >> 6) & 15, qd = n & 63;
          int b = m >> 11, c = m & 2047;
          ((short*)Cout)[(size_t)sel * 8388608 + ((size_t)(b * 16 + h) * 2048 + c) * 64 + qd] =
              (short)f2bf(val);
        } else {
          ((float*)Cout)[(size_t)m * N + n] = val;
        }
      }
    }
  }
}

// ---------------- causal flash attention ----------------
// 64 q-rows/WG (wave = 16 q), pair-complement over 32 q-blocks: WG (qbp,bh)
// does qb = qbp and 31-qbp => 33 kv-iters each, perfectly balanced.
// Flat grid wg = qbp*64 + bh: same-bh WGs differ by 64 = 0 mod 8 -> same XCD
// (K/V stays L2-resident; 8 bh per XCD = ~4MB).
__global__ __launch_bounds__(256) void attn_fwd(const short* __restrict__ qkv,
                                                short* __restrict__ y2) {
  __shared__ short Ks[64 * 64];  // [kv][kd] xor-swizzled: byte ^= (kv&7)<<4
  __shared__ short Vt[64 * 64];  // col-major [vd][kv], byte ^= (vd&7)<<4
  const int tid = threadIdx.x;
  const int l = tid & 63, w = tid >> 6;
  const int g = l >> 4, lr = l & 15;
  const int wg = blockIdx.x;
  const int qbp = wg >> 6;   // 0..15
  const int bh = wg & 63;
  const short* qp = qkv + (size_t)bh * 131072;
  const short* kp = qp + 8388608;
  const short* vp = qp + 16777216;
  const int b = bh >> 4, h = bh & 15;
  const int vkv0 = (tid >> 4) * 4;   // V staging: this thread's 4 kv rows
  const int vvd4 = (tid & 15) * 4;   // and 4 vd columns
#pragma unroll 1
  for (int pass = 0; pass < 2; ++pass) {
    const int qb = pass ? (31 - qbp) : qbp;
    const int qw = qb * 64 + w * 16;
    bf16x8 qf[2];  // B-operand of S^T: b[i]=Q[q=lr][kc*32+g*8+i]
#pragma unroll
    for (int kc = 0; kc < 2; ++kc)
      qf[kc] = *(const bf16x8*)&qp[(qw + lr) * 64 + kc * 32 + g * 8];
    float mrun = -__builtin_inff();
    float lrun = 0.f;
    f32x4 acc[4] = {};  // y^T: [vd-tile], row=vd, col=q
    const int nkv = qb + 1;
    for (int kvb = 0; kvb < nkv; ++kvb) {
      const int kv0 = kvb * 64;
      // stage K via global_load_lds, source pre-swizzled (both-sides rule)
#pragma unroll
      for (int j = 0; j < 2; ++j) {
        int r0 = (w * 2 + j) * 8;
        int r = r0 + (l >> 3);
        int sb = ((l & 7) * 16) ^ ((r & 7) << 4);
        __builtin_amdgcn_global_load_lds(AS1(kp + (size_t)(kv0 + r) * 64 + (sb >> 1)),
                                         AS3(&Ks[r0 * 64]), 16, 0, 0);
      }
      // stage V: 4 coalesced b64 row loads -> in-lane 4x4 bf16 transpose -> 4x ds_write_b64
      {
        const short* vrow = vp + (size_t)(kv0 + vkv0) * 64 + vvd4;
        s16x4 r0 = *(const s16x4*)(vrow);
        s16x4 r1 = *(const s16x4*)(vrow + 64);
        s16x4 r2 = *(const s16x4*)(vrow + 128);
        s16x4 r3 = *(const s16x4*)(vrow + 192);
        unsigned q0 = ((const unsigned*)&r0)[0], q1 = ((const unsigned*)&r0)[1];
        unsigned q2 = ((const unsigned*)&r1)[0], q3 = ((const unsigned*)&r1)[1];
        unsigned q4 = ((const unsigned*)&r2)[0], q5 = ((const unsigned*)&r2)[1];
        unsigned q6 = ((const unsigned*)&r3)[0], q7 = ((const unsigned*)&r3)[1];
#pragma unroll
        for (int c = 0; c < 4; ++c) {
          unsigned selb = (c & 1) ? 0x07060302u : 0x05040100u;
          unsigned lodw = (c < 2) ? __builtin_amdgcn_perm(q2, q0, selb)
                                  : __builtin_amdgcn_perm(q3, q1, selb);
          unsigned hidw = (c < 2) ? __builtin_amdgcn_perm(q6, q4, selb)
                                  : __builtin_amdgcn_perm(q7, q5, selb);
          int vd = vvd4 + c;
          int byte = vd * 128 + ((vkv0 * 2) ^ ((vd & 7) << 4));
          u32x2 wv; wv[0] = lodw; wv[1] = hidw;
          *(u32x2*)&Vt[byte >> 1] = wv;
        }
      }
      __syncthreads();
      if (kv0 <= qw + 15) {  // wave-uniform
        const bool needmask = (kv0 + 63 > qw);
        f32x4 st[4];
#pragma unroll
        for (int kt = 0; kt < 4; ++kt) {
          int r = kt * 16 + lr;
          int swz = (r & 7) << 4;
          bf16x8 kf0 = *(const bf16x8*)&Ks[(r * 128 + ((g * 16) ^ swz)) >> 1];
          bf16x8 kf1 = *(const bf16x8*)&Ks[(r * 128 + ((64 + g * 16) ^ swz)) >> 1];
          f32x4 z = {0.f, 0.f, 0.f, 0.f};
          z = __builtin_amdgcn_mfma_f32_16x16x32_bf16(kf0, qf[0], z, 0, 0, 0);
          z = __builtin_amdgcn_mfma_f32_16x16x32_bf16(kf1, qf[1], z, 0, 0, 0);
          st[kt] = z;  // S^T[kv=16kt+4g+i][q=lr]  (base-2 logits)
        }
        if (needmask) {
#pragma unroll
          for (int kt = 0; kt < 4; ++kt)
#pragma unroll
            for (int i = 0; i < 4; ++i) {
              int kvg = kv0 + kt * 16 + g * 4 + i;
              if (kvg > qw + lr) st[kt][i] = -__builtin_inff();
            }
        }
        // running max with defer (T13): skip rescale while pm <= mrun + 8
        float pm = -__builtin_inff();
#pragma unroll
        for (int kt = 0; kt < 4; ++kt)
#pragma unroll
          for (int i = 0; i < 4; ++i) pm = fmaxf(pm, st[kt][i]);
        pm = fmaxf(pm, __shfl_xor(pm, 16));
        pm = fmaxf(pm, __shfl_xor(pm, 32));
        if (!__all(pm <= mrun + 8.f)) {
          float mnew = fmaxf(mrun, pm);
          float scale = EXP2(mrun - mnew);
          mrun = mnew;
          lrun *= scale;
#pragma unroll
          for (int vt = 0; vt < 4; ++vt) acc[vt] *= scale;
        }
        float rs = 0.f;
        unsigned pk[4][2];
#pragma unroll
        for (int kt = 0; kt < 4; ++kt) {
#pragma unroll
          for (int i = 0; i < 4; ++i) {
            float e = EXP2(st[kt][i] - mrun);
            st[kt][i] = e;
            rs += e;
          }
          pk[kt][0] = pack2bf(st[kt][0], st[kt][1]);
          pk[kt][1] = pack2bf(st[kt][2], st[kt][3]);
        }
        rs += __shfl_xor(rs, 16);
        rs += __shfl_xor(rs, 32);
        lrun += rs;
        // PV: y^T += V^T * P^T via mfma 16x16x16; B-frag is the lane's own pk.
#pragma unroll
        for (int kt = 0; kt < 4; ++kt) {
          s16x4 pb;
          ((unsigned*)&pb)[0] = pk[kt][0];
          ((unsigned*)&pb)[1] = pk[kt][1];
#pragma unroll
          for (int vt = 0; vt < 4; ++vt) {
            int vd = vt * 16 + lr;
            s16x4 vf4 = *(const s16x4*)&Vt[(vd * 128 + ((kt * 32 + g * 8) ^ ((vd & 7) << 4))) >> 1];
            acc[vt] = mfma16(vf4, pb, acc[vt]);
          }
        }
      }
      __syncthreads();
    }
    float inv = 1.f / lrun;
    int qg = qw + lr;
#pragma unroll
    for (int vt = 0; vt < 4; ++vt) {
      s16x4 o;
#pragma unroll
      for (int j = 0; j < 4; ++j) o[j] = (short)f2bf(acc[vt][j] * inv);
      *(s16x4*)&y2[((size_t)(b * 2048 + qg)) * 1024 + h * 64 + vt * 16 + g * 4] = o;
    }
  }
}

extern "C" void kernel_launch(void* const* d_in, const int* in_sizes, int n_in,
                              void* d_out, int out_size, void* d_ws, size_t ws_size,
                              hipStream_t stream) {
  const float* x = (const float*)d_in[0];
  const float* Q = (const float*)d_in[1];
  const float* K = (const float*)d_in[2];
  const float* V = (const float*)d_in[3];
  const float* W = (const float*)d_in[4];
  char* ws = (char*)d_ws;
  short* WqkvT = (short*)ws;                           //  6,291,456 B
  short* xb    = (short*)(ws + 6291456);               // 16,777,216 B
  short* qkv   = (short*)(ws + 23068672);              // 50,331,648 B
  short* WoT   = (short*)(ws + 73400320);              //  2,097,152 B
  short* y2    = xb;  // alias: xb dead after QKV GEMM
  float* z     = (float*)d_out;

  pack_wqkv<<<3072, 256, 0, stream>>>(Q, K, V, WqkvT);
  pack_wo<<<1024, 256, 0, stream>>>(W, WoT);
  pack_xk<<<8192, 256, 0, stream>>>(x, xb);
  gemm_bt<0><<<dim3(24, 64), 256, 0, stream>>>(xb, WqkvT, (void*)qkv, 8192, 3072, 1024);
  attn_fwd<<<1024, 256, 0, stream>>>(qkv, y2);
  gemm_bt<1><<<dim3(8, 64), 256, 0, stream>>>(y2, WoT, (void*)z, 8192, 1024, 1024);
}

// Round 6
// 274.959 us; speedup vs baseline: 1.0929x; 1.0929x over previous
//
#include <hip/hip_runtime.h>
#include <hip/hip_bf16.h>

typedef __attribute__((ext_vector_type(8))) short bf16x8;
typedef __attribute__((ext_vector_type(4))) short s16x4;
typedef __attribute__((ext_vector_type(4))) float f32x4;

#define AS1(p) ((const __attribute__((address_space(1))) void*)(p))
#define AS3(p) ((__attribute__((address_space(3))) void*)(p))
#define EXP2(x) __builtin_amdgcn_exp2f(x)

__device__ __forceinline__ unsigned short f2bf(float f) {
  __hip_bfloat16 h = __float2bfloat16(f);
  union { __hip_bfloat16 h; unsigned short s; } u; u.h = h; return u.s;
}
__device__ __forceinline__ unsigned pack2bf(float a, float b) {
  return ((unsigned)f2bf(b) << 16) | (unsigned)f2bf(a);
}

// PV matmul: 16x16x16 bf16 MFMA — A/B layouts match the QK^T D-layout in-lane.
__device__ __forceinline__ f32x4 mfma16(s16x4 a, s16x4 b, f32x4 c) {
#if __has_builtin(__builtin_amdgcn_mfma_f32_16x16x16bf16_1k)
  return __builtin_amdgcn_mfma_f32_16x16x16bf16_1k(a, b, c, 0, 0, 0);
#else
  f32x4 d = c;
  asm volatile("v_mfma_f32_16x16x16_bf16 %0, %1, %2, %0" : "+v"(d) : "v"(a), "v"(b));
  return d;
#endif
}

// ---------------- pack kernels (coalesced reads) ----------------
__global__ void pack_wqkv(const float* __restrict__ Q, const float* __restrict__ K,
                          const float* __restrict__ V, short* __restrict__ WqkvT) {
  int idx = blockIdx.x * 256 + threadIdx.x;   // 786432 threads total
  int sq = idx >> 12;                         // sel*64 + qd, 0..191
  int r = idx & 4095;
  int sel = sq >> 6, qd = sq & 63;
  const float* src = (sel == 0) ? Q : (sel == 1) ? K : V;
  float scale = (sel == 0) ? (0.03125f * 1.44269504f) : (sel == 1) ? 0.03125f : 0.25f;
  f32x4 v = *(const f32x4*)(src + (size_t)qd * 16384 + r * 4);
  int d = r >> 2, hb = (r & 3) * 4;
#pragma unroll
  for (int j = 0; j < 4; ++j)
    WqkvT[(size_t)(sel * 1024 + (hb + j) * 64 + qd) * 1024 + d] = (short)f2bf(v[j] * scale);
}

__global__ void pack_wo(const float* __restrict__ W, short* __restrict__ WoT) {
  int dcol = blockIdx.x;
  int t = threadIdx.x;  // 256 threads cover 1024 f32
  f32x4 v = *(const f32x4*)(W + (size_t)dcol * 1024 + t * 4);
  int vd = t >> 2, hb = (t & 3) * 4;
#pragma unroll
  for (int j = 0; j < 4; ++j)
    WoT[(size_t)dcol * 1024 + (hb + j) * 64 + vd] = (short)f2bf(v[j] * 0.25f);
}

__global__ void pack_xk(const float* __restrict__ x, short* __restrict__ xb) {
  int i = blockIdx.x * 256 + threadIdx.x;  // groups of 4 floats
  if (i >= 2097152) return;
  f32x4 v = ((const f32x4*)x)[i];
  s16x4 o;
#pragma unroll
  for (int j = 0; j < 4; ++j) o[j] = (short)f2bf(v[j]);
  ((s16x4*)xb)[i] = o;
}

// ---------------- GEMM: C[M,N] = A[M,K] * Bt[N,K]^T  (m97 structure) ----------------
// MODE 0: QKV output. Q,K thirds -> per-head [b*16+h][c][qd] bf16.
//         V third -> per-head TRANSPOSED [b*16+h][vd][c] bf16 (b64 stores, cheap).
// MODE 1: f32 row-major output.
template <int MODE>
__global__ __launch_bounds__(256) void gemm_bt(const short* __restrict__ A,
                                               const short* __restrict__ Bt,
                                               void* __restrict__ Cout,
                                               int M, int N, int K) {
  __shared__ short As[128 * 64];
  __shared__ short Bs[128 * 64];
  const int tid = threadIdx.x;
  const int l = tid & 63, w = tid >> 6;
  const int g = l >> 4, lr = l & 15;
  const int m0 = blockIdx.y * 128, n0 = blockIdx.x * 128;
  const int wm = w >> 1, wn = w & 1;
  const int sr = l >> 3, sc = (l & 7) * 8;
  f32x4 acc[4][4] = {};
  for (int k0 = 0; k0 < K; k0 += 64) {
#pragma unroll
    for (int j = 0; j < 4; ++j) {
      int r0 = (w * 4 + j) * 8;
      __builtin_amdgcn_global_load_lds(AS1(A + (size_t)(m0 + r0 + sr) * K + k0 + sc),
                                       AS3(&As[r0 * 64]), 16, 0, 0);
      __builtin_amdgcn_global_load_lds(AS1(Bt + (size_t)(n0 + r0 + sr) * K + k0 + sc),
                                       AS3(&Bs[r0 * 64]), 16, 0, 0);
    }
    __syncthreads();
#pragma unroll
    for (int kc = 0; kc < 2; ++kc) {
      bf16x8 af[4], bfr[4];
#pragma unroll
      for (int i = 0; i < 4; ++i) {
        af[i]  = *(const bf16x8*)&As[(wm * 64 + i * 16 + lr) * 64 + kc * 32 + g * 8];
        bfr[i] = *(const bf16x8*)&Bs[(wn * 64 + i * 16 + lr) * 64 + kc * 32 + g * 8];
      }
#pragma unroll
      for (int mi = 0; mi < 4; ++mi)
#pragma unroll
        for (int ni = 0; ni < 4; ++ni)
          acc[mi][ni] = __builtin_amdgcn_mfma_f32_16x16x32_bf16(af[mi], bfr[ni], acc[mi][ni], 0, 0, 0);
    }
    __syncthreads();
  }
  const int sel = n0 >> 10;  // uniform per block (128 | 1024)
#pragma unroll
  for (int mi = 0; mi < 4; ++mi) {
#pragma unroll
    for (int ni = 0; ni < 4; ++ni) {
      if (MODE == 0 && sel == 2) {
        // V^T: 4 j's are c-contiguous -> one b64 store.
        int m = m0 + wm * 64 + mi * 16 + g * 4;
        int n = n0 + wn * 64 + ni * 16 + lr;
        int h = (n >> 6) & 15, vd = n & 63;
        int b = m >> 11, c = m & 2047;
        s16x4 o;
#pragma unroll
        for (int j = 0; j < 4; ++j) o[j] = (short)f2bf(acc[mi][ni][j]);
        *(s16x4*)&((short*)Cout)[16777216 + (size_t)(b * 16 + h) * 131072 +
                                 (size_t)vd * 2048 + c] = o;
      } else {
#pragma unroll
        for (int j = 0; j < 4; ++j) {
          int m = m0 + wm * 64 + mi * 16 + g * 4 + j;
          int n = n0 + wn * 64 + ni * 16 + lr;
          float val = acc[mi][ni][j];
          if (MODE == 0) {
            int h = (n >> 6) & 15, qd = n & 63;
            int b = m >> 11, c = m & 2047;
            ((short*)Cout)[(size_t)sel * 8388608 + ((size_t)(b * 16 + h) * 2048 + c) * 64 + qd] =
                (short)f2bf(val);
          } else {
            ((float*)Cout)[(size_t)m * N + n] = val;
          }
        }
      }
    }
  }
}

// ---------------- causal flash attention ----------------
// 64 q-rows/WG (wave = 16 q), pair-complement over 32 q-blocks: WG (qbp,bh)
// does qb = qbp and 31-qbp => 33 kv-iters each, perfectly balanced.
// Flat grid wg = qbp*64 + bh: same-bh WGs land on the same XCD (wg%8=bh%8).
// K and V^T both staged via global_load_lds with pre-swizzled source.
// Fixed-max softmax (M=8 base-2): logits = q.k/1024, |logit| << 1, so no
// running max / rescale needed; masked lanes exp2(-inf)=0.
__global__ __launch_bounds__(256) void attn_fwd(const short* __restrict__ qkv,
                                                short* __restrict__ y2) {
  __shared__ short Ks[64 * 64];  // [kv][kd] xor-swizzled: byte ^= (kv&7)<<4
  __shared__ short Vt[64 * 64];  // [vd][kv] xor-swizzled: byte ^= (vd&7)<<4
  const int tid = threadIdx.x;
  const int l = tid & 63, w = tid >> 6;
  const int g = l >> 4, lr = l & 15;
  const int wg = blockIdx.x;
  const int qbp = wg >> 6;   // 0..15
  const int bh = wg & 63;
  const short* qp = qkv + (size_t)bh * 131072;
  const short* kp = qp + 8388608;
  const short* vtp = qkv + 16777216 + (size_t)bh * 131072;  // [vd][2048]
  const int b = bh >> 4, h = bh & 15;
#pragma unroll 1
  for (int pass = 0; pass < 2; ++pass) {
    const int qb = pass ? (31 - qbp) : qbp;
    const int qw = qb * 64 + w * 16;
    bf16x8 qf[2];  // B-operand of S^T: b[i]=Q[q=lr][kc*32+g*8+i]
#pragma unroll
    for (int kc = 0; kc < 2; ++kc)
      qf[kc] = *(const bf16x8*)&qp[(qw + lr) * 64 + kc * 32 + g * 8];
    float lrun = 0.f;
    f32x4 acc[4] = {};  // y^T: [vd-tile], row=vd, col=q
    const int nkv = qb + 1;
    for (int kvb = 0; kvb < nkv; ++kvb) {
      const int kv0 = kvb * 64;
      // stage K and V^T via global_load_lds, sources pre-swizzled
#pragma unroll
      for (int j = 0; j < 2; ++j) {
        int r0 = (w * 2 + j) * 8;
        int r = r0 + (l >> 3);
        int sb = ((l & 7) * 16) ^ ((r & 7) << 4);
        __builtin_amdgcn_global_load_lds(AS1(kp + (size_t)(kv0 + r) * 64 + (sb >> 1)),
                                         AS3(&Ks[r0 * 64]), 16, 0, 0);
        __builtin_amdgcn_global_load_lds(AS1(vtp + (size_t)r * 2048 + kv0 + (sb >> 1)),
                                         AS3(&Vt[r0 * 64]), 16, 0, 0);
      }
      __syncthreads();
      {
        const bool needmask = (kv0 + 63 > qw);
        f32x4 st[4];
#pragma unroll
        for (int kt = 0; kt < 4; ++kt) {
          int r = kt * 16 + lr;
          int swz = (r & 7) << 4;
          bf16x8 kf0 = *(const bf16x8*)&Ks[(r * 128 + ((g * 16) ^ swz)) >> 1];
          bf16x8 kf1 = *(const bf16x8*)&Ks[(r * 128 + ((64 + g * 16) ^ swz)) >> 1];
          f32x4 z = {0.f, 0.f, 0.f, 0.f};
          z = __builtin_amdgcn_mfma_f32_16x16x32_bf16(kf0, qf[0], z, 0, 0, 0);
          z = __builtin_amdgcn_mfma_f32_16x16x32_bf16(kf1, qf[1], z, 0, 0, 0);
          st[kt] = z;  // S^T[kv=16kt+4g+i][q=lr]  (base-2 logits)
        }
        if (needmask) {
#pragma unroll
          for (int kt = 0; kt < 4; ++kt)
#pragma unroll
            for (int i = 0; i < 4; ++i) {
              int kvg = kv0 + kt * 16 + g * 4 + i;
              if (kvg > qw + lr) st[kt][i] = -__builtin_inff();
            }
        }
        // fixed-max softmax: P = 2^(s - 8)
        float rs = 0.f;
        unsigned pk[4][2];
#pragma unroll
        for (int kt = 0; kt < 4; ++kt) {
#pragma unroll
          for (int i = 0; i < 4; ++i) {
            float e = EXP2(st[kt][i] - 8.f);
            st[kt][i] = e;
            rs += e;
          }
          pk[kt][0] = pack2bf(st[kt][0], st[kt][1]);
          pk[kt][1] = pack2bf(st[kt][2], st[kt][3]);
        }
        rs += __shfl_xor(rs, 16);
        rs += __shfl_xor(rs, 32);
        lrun += rs;
        // PV: y^T += V^T * P^T via mfma 16x16x16; B-frag is the lane's own pk.
#pragma unroll
        for (int kt = 0; kt < 4; ++kt) {
          s16x4 pb;
          ((unsigned*)&pb)[0] = pk[kt][0];
          ((unsigned*)&pb)[1] = pk[kt][1];
#pragma unroll
          for (int vt = 0; vt < 4; ++vt) {
            int vd = vt * 16 + lr;
            s16x4 vf4 = *(const s16x4*)&Vt[(vd * 128 + ((kt * 32 + g * 8) ^ ((vd & 7) << 4))) >> 1];
            acc[vt] = mfma16(vf4, pb, acc[vt]);
          }
        }
      }
      __syncthreads();
    }
    float inv = 1.f / lrun;
    int qg = qw + lr;
#pragma unroll
    for (int vt = 0; vt < 4; ++vt) {
      s16x4 o;
#pragma unroll
      for (int j = 0; j < 4; ++j) o[j] = (short)f2bf(acc[vt][j] * inv);
      *(s16x4*)&y2[((size_t)(b * 2048 + qg)) * 1024 + h * 64 + vt * 16 + g * 4] = o;
    }
  }
}

extern "C" void kernel_launch(void* const* d_in, const int* in_sizes, int n_in,
                              void* d_out, int out_size, void* d_ws, size_t ws_size,
                              hipStream_t stream) {
  const float* x = (const float*)d_in[0];
  const float* Q = (const float*)d_in[1];
  const float* K = (const float*)d_in[2];
  const float* V = (const float*)d_in[3];
  const float* W = (const float*)d_in[4];
  char* ws = (char*)d_ws;
  short* WqkvT = (short*)ws;                           //  6,291,456 B
  short* xb    = (short*)(ws + 6291456);               // 16,777,216 B
  short* qkv   = (short*)(ws + 23068672);              // 50,331,648 B
  short* WoT   = (short*)(ws + 73400320);              //  2,097,152 B
  short* y2    = xb;  // alias: xb dead after QKV GEMM
  float* z     = (float*)d_out;

  pack_wqkv<<<3072, 256, 0, stream>>>(Q, K, V, WqkvT);
  pack_wo<<<1024, 256, 0, stream>>>(W, WoT);
  pack_xk<<<8192, 256, 0, stream>>>(x, xb);
  gemm_bt<0><<<dim3(24, 64), 256, 0, stream>>>(xb, WqkvT, (void*)qkv, 8192, 3072, 1024);
  attn_fwd<<<1024, 256, 0, stream>>>(qkv, y2);
  gemm_bt<1><<<dim3(8, 64), 256, 0, stream>>>(y2, WoT, (void*)z, 8192, 1024, 1024);
}